// Round 2
// baseline (479.231 us; speedup 1.0000x reference)
//
#include <hip/hip_runtime.h>
#include <stdint.h>

typedef __attribute__((ext_vector_type(8))) short short8;
typedef __attribute__((ext_vector_type(4))) float floatx4;

__device__ __forceinline__ float b2f(unsigned short u) {
  union { unsigned int i; float f; } v; v.i = ((unsigned int)u) << 16; return v.f;
}
__device__ __forceinline__ unsigned short f2b(float f) {
  union { float f; unsigned int i; } v; v.f = f;
  unsigned int i = v.i;
  return (unsigned short)((i + 0x7FFFu + ((i >> 16) & 1u)) >> 16);
}

// global -> LDS 16B per lane. lds_base must be wave-uniform; HW adds lane*16B.
__device__ __forceinline__ void stage16(const unsigned short* g, unsigned short* lds_base, int lane) {
#if __has_builtin(__builtin_amdgcn_global_load_lds)
  __builtin_amdgcn_global_load_lds((__attribute__((address_space(1))) const unsigned int*)g,
                                   (__attribute__((address_space(3))) unsigned int*)lds_base,
                                   16, 0, 0);
#else
  *(short8*)(lds_base + lane * 8) = *(const short8*)g;
#endif
}

// C = A[M][K] @ Bt[N][K]^T, bf16 in, fp32 accum. Output either bf16 (Cb) or fp32 (Cf).
// Optional rowdiv (row scaled by 1/rowdiv[row]) and fp32 bias per col.
// 128x128 tile, BK=32, 4 waves (2x2), 4x4 16x16x32 MFMA per wave.
__global__ __launch_bounds__(256) void gemm_bt(
    const unsigned short* __restrict__ A, const unsigned short* __restrict__ B,
    unsigned short* __restrict__ Cb, float* __restrict__ Cf,
    const float* __restrict__ rowdiv, const float* __restrict__ bias,
    int K, int lda, int ldb, int ldc,
    long long sA, long long sB, long long sC, long long sRD)
{
  const int tid  = threadIdx.x;
  const int lane = tid & 63;
  const int wave = tid >> 6;
  const int wr = wave >> 1, wc = wave & 1;
  const int m0 = blockIdx.y * 128;
  const int n0 = blockIdx.x * 128;
  const int bz = blockIdx.z;
  A += (long long)bz * sA;
  B += (long long)bz * sB;
  const float* rd = rowdiv ? rowdiv + (long long)bz * sRD : (const float*)0;

  __shared__ unsigned short As[128 * 32];
  __shared__ unsigned short Bs[128 * 32];

  floatx4 acc[4][4];
#pragma unroll
  for (int i = 0; i < 4; ++i)
#pragma unroll
    for (int j = 0; j < 4; ++j) acc[i][j] = floatx4{0.f, 0.f, 0.f, 0.f};

  const int srow = wave * 32 + (lane >> 2);
  const int scol = (lane & 3) * 8;
  const unsigned short* ga0 = A + (long long)(m0 + srow) * lda + scol;
  const unsigned short* ga1 = ga0 + 16LL * lda;
  const unsigned short* gb0 = B + (long long)(n0 + srow) * ldb + scol;
  const unsigned short* gb1 = gb0 + 16LL * ldb;
  unsigned short* lA0 = As + (wave * 32) * 32;
  unsigned short* lA1 = As + (wave * 32 + 16) * 32;
  unsigned short* lB0 = Bs + (wave * 32) * 32;
  unsigned short* lB1 = Bs + (wave * 32 + 16) * 32;

  const int l15 = lane & 15;
  const int q8  = (lane >> 4) * 8;

  for (int kt = 0; kt < K; kt += 32) {
    __syncthreads();
    stage16(ga0 + kt, lA0, lane);
    stage16(ga1 + kt, lA1, lane);
    stage16(gb0 + kt, lB0, lane);
    stage16(gb1 + kt, lB1, lane);
    __syncthreads();
    short8 af[4], bfv[4];
#pragma unroll
    for (int i = 0; i < 4; ++i) af[i]  = *(const short8*)&As[(wr * 64 + i * 16 + l15) * 32 + q8];
#pragma unroll
    for (int j = 0; j < 4; ++j) bfv[j] = *(const short8*)&Bs[(wc * 64 + j * 16 + l15) * 32 + q8];
#pragma unroll
    for (int i = 0; i < 4; ++i)
#pragma unroll
      for (int j = 0; j < 4; ++j)
        acc[i][j] = __builtin_amdgcn_mfma_f32_16x16x32_bf16(af[i], bfv[j], acc[i][j], 0, 0, 0);
  }

  const int q4 = (lane >> 4) * 4;
#pragma unroll
  for (int i = 0; i < 4; ++i) {
#pragma unroll
    for (int j = 0; j < 4; ++j) {
      const int col = n0 + wc * 64 + j * 16 + l15;
      const float bi = bias ? bias[col] : 0.0f;
#pragma unroll
      for (int r = 0; r < 4; ++r) {
        const int row = m0 + wr * 64 + i * 16 + q4 + r;
        float v = acc[i][j][r];
        if (rd) v = v / rd[row];
        v += bi;
        if (Cb) Cb[(long long)bz * sC + (long long)row * ldc + col] = f2b(v);
        else    Cf[(long long)bz * sC + (long long)row * ldc + col] = v;
      }
    }
  }
}

// Fused scores + group + exp: W[b][m][n] = exp(q.k*scale) * (a + (1-a)*gw_m.gw_n)
// L[b*1024+m] += sum_n exp(q.k*scale)   (unnormalized softmax denom)
__global__ __launch_bounds__(256) void score_weights(
    const unsigned short* __restrict__ qkv, const unsigned short* __restrict__ gw,
    unsigned short* __restrict__ Wout, float* __restrict__ L,
    const float* __restrict__ alpha)
{
  const int tid  = threadIdx.x;
  const int lane = tid & 63;
  const int wave = tid >> 6;
  const int wr = wave >> 1, wc = wave & 1;
  const int n0 = blockIdx.x * 128;
  const int m0 = blockIdx.y * 128;
  const int b  = blockIdx.z;

  const unsigned short* Aq = qkv + ((long long)(b * 1024 + m0)) * 2304;        // q: cols 0..767
  const unsigned short* Bk = qkv + ((long long)(b * 1024 + n0)) * 2304 + 768;  // k: cols 768..1535

  __shared__ unsigned short As[128 * 32];
  __shared__ unsigned short Bs[128 * 32];

  floatx4 sacc[4][4];
#pragma unroll
  for (int i = 0; i < 4; ++i)
#pragma unroll
    for (int j = 0; j < 4; ++j) sacc[i][j] = floatx4{0.f, 0.f, 0.f, 0.f};

  const int srow = wave * 32 + (lane >> 2);
  const int scol = (lane & 3) * 8;
  const unsigned short* ga0 = Aq + (long long)srow * 2304 + scol;
  const unsigned short* ga1 = ga0 + 16LL * 2304;
  const unsigned short* gb0 = Bk + (long long)srow * 2304 + scol;
  const unsigned short* gb1 = gb0 + 16LL * 2304;
  unsigned short* lA0 = As + (wave * 32) * 32;
  unsigned short* lA1 = As + (wave * 32 + 16) * 32;
  unsigned short* lB0 = Bs + (wave * 32) * 32;
  unsigned short* lB1 = Bs + (wave * 32 + 16) * 32;

  const int l15 = lane & 15;
  const int q8  = (lane >> 4) * 8;

  for (int kt = 0; kt < 768; kt += 32) {
    __syncthreads();
    stage16(ga0 + kt, lA0, lane);
    stage16(ga1 + kt, lA1, lane);
    stage16(gb0 + kt, lB0, lane);
    stage16(gb1 + kt, lB1, lane);
    __syncthreads();
    short8 af[4], bfv[4];
#pragma unroll
    for (int i = 0; i < 4; ++i) af[i]  = *(const short8*)&As[(wr * 64 + i * 16 + l15) * 32 + q8];
#pragma unroll
    for (int j = 0; j < 4; ++j) bfv[j] = *(const short8*)&Bs[(wc * 64 + j * 16 + l15) * 32 + q8];
#pragma unroll
    for (int i = 0; i < 4; ++i)
#pragma unroll
      for (int j = 0; j < 4; ++j)
        sacc[i][j] = __builtin_amdgcn_mfma_f32_16x16x32_bf16(af[i], bfv[j], sacc[i][j], 0, 0, 0);
  }

  // group: gw is [16384][64] bf16 (cols 49..63 zero). K=64 -> 2 MFMA k-steps, frags direct from global.
  const unsigned short* gq = gw + ((long long)(b * 1024 + m0 + wr * 64)) * 64;
  const unsigned short* gk = gw + ((long long)(b * 1024 + n0 + wc * 64)) * 64;
  floatx4 gacc[4][4];
#pragma unroll
  for (int i = 0; i < 4; ++i)
#pragma unroll
    for (int j = 0; j < 4; ++j) gacc[i][j] = floatx4{0.f, 0.f, 0.f, 0.f};
#pragma unroll
  for (int ks = 0; ks < 2; ++ks) {
    short8 af[4], bfv[4];
#pragma unroll
    for (int i = 0; i < 4; ++i) af[i]  = *(const short8*)&gq[(long long)(i * 16 + l15) * 64 + ks * 32 + q8];
#pragma unroll
    for (int j = 0; j < 4; ++j) bfv[j] = *(const short8*)&gk[(long long)(j * 16 + l15) * 64 + ks * 32 + q8];
#pragma unroll
    for (int i = 0; i < 4; ++i)
#pragma unroll
      for (int j = 0; j < 4; ++j)
        gacc[i][j] = __builtin_amdgcn_mfma_f32_16x16x32_bf16(af[i], bfv[j], gacc[i][j], 0, 0, 0);
  }

  const float aa    = 1.0f / (1.0f + __expf(-alpha[0]));
  const float onema = 1.0f - aa;
  const float scale = 0.03608439182435161f;  // 768^-0.5
  unsigned short* Wb = Wout + ((long long)b << 20);
  const int q4 = (lane >> 4) * 4;

  float ls[4][4];
#pragma unroll
  for (int i = 0; i < 4; ++i)
#pragma unroll
    for (int r = 0; r < 4; ++r) ls[i][r] = 0.0f;

#pragma unroll
  for (int i = 0; i < 4; ++i) {
#pragma unroll
    for (int j = 0; j < 4; ++j) {
      const int col = n0 + wc * 64 + j * 16 + l15;
#pragma unroll
      for (int r = 0; r < 4; ++r) {
        const int row = m0 + wr * 64 + i * 16 + q4 + r;
        const float e = __expf(sacc[i][j][r] * scale);
        const float g = aa + onema * gacc[i][j][r];
        Wb[(long long)row * 1024 + col] = f2b(e * g);
        ls[i][r] += e;
      }
    }
  }
  // reduce partial row sums across the 16 lanes sharing a row, then atomic per row
#pragma unroll
  for (int i = 0; i < 4; ++i) {
#pragma unroll
    for (int r = 0; r < 4; ++r) {
      float v = ls[i][r];
      v += __shfl_xor(v, 1, 64);
      v += __shfl_xor(v, 2, 64);
      v += __shfl_xor(v, 4, 64);
      v += __shfl_xor(v, 8, 64);
      if (l15 == 0) {
        const int row = m0 + wr * 64 + i * 16 + q4 + r;
        atomicAdd(&L[b * 1024 + row], v);
      }
    }
  }
}

// gw[row][0..63] = softmax(q_row @ W_gp) padded with zeros (cols 49..63).
// One wave per row; WgpT is [49][768] bf16 (pre-transposed) for coalesced dots.
__global__ __launch_bounds__(256) void gw_kernel(
    const unsigned short* __restrict__ qkv, const unsigned short* __restrict__ WgpT,
    unsigned short* __restrict__ gw)
{
  const int wave = threadIdx.x >> 6;
  const int lane = threadIdx.x & 63;
  const long long row = (long long)blockIdx.x * 4 + wave;
  const unsigned short* q = qkv + row * 2304;
  float qv[12];
#pragma unroll
  for (int j = 0; j < 12; ++j) qv[j] = b2f(q[lane + 64 * j]);

  float logit = -1e30f;
  for (int g = 0; g < 49; ++g) {
    const unsigned short* wg = WgpT + g * 768;
    float acc = 0.0f;
#pragma unroll
    for (int j = 0; j < 12; ++j) acc += qv[j] * b2f(wg[lane + 64 * j]);
#pragma unroll
    for (int m = 1; m < 64; m <<= 1) acc += __shfl_xor(acc, m, 64);
    if (lane == g) logit = acc;
  }
  float mx = logit;
#pragma unroll
  for (int m = 1; m < 64; m <<= 1) mx = fmaxf(mx, __shfl_xor(mx, m, 64));
  const float e = (lane < 49) ? __expf(logit - mx) : 0.0f;
  float s = e;
#pragma unroll
  for (int m = 1; m < 64; m <<= 1) s += __shfl_xor(s, m, 64);
  gw[row * 64 + lane] = f2b(e / s);
}

// fp32 -> bf16 elementwise, 4/thread (n divisible by 1024)
__global__ void convert_f2b(const float* __restrict__ in, unsigned short* __restrict__ out, long long n)
{
  long long i = ((long long)blockIdx.x * 256 + threadIdx.x) * 4;
  if (i + 3 >= n) {
    for (long long k = i; k < n; ++k) out[k] = f2b(in[k]);
    return;
  }
  float4 v = *(const float4*)(in + i);
  out[i + 0] = f2b(v.x);
  out[i + 1] = f2b(v.y);
  out[i + 2] = f2b(v.z);
  out[i + 3] = f2b(v.w);
}

// fp32 in -> bf16 transposed out: out[C][R] = in[R][C]^T
__global__ void transpose_f2b(const float* __restrict__ in, unsigned short* __restrict__ out,
                              int R, int C, int ldin, int ldout)
{
  __shared__ unsigned short t[32][33];
  const int c0 = blockIdx.x * 32, r0 = blockIdx.y * 32;
  for (int i = threadIdx.y; i < 32; i += 8) {
    const int r = r0 + i, c = c0 + threadIdx.x;
    if (r < R && c < C) t[i][threadIdx.x] = f2b(in[(long long)r * ldin + c]);
  }
  __syncthreads();
  for (int i = threadIdx.y; i < 32; i += 8) {
    const int r = c0 + i, c = r0 + threadIdx.x;
    if (r < C && c < R) out[(long long)r * ldout + c] = t[threadIdx.x][i];
  }
}

// bf16 transpose with batch strides: out[C][R] = in[R][C]^T
__global__ void transpose_bf16(const unsigned short* __restrict__ in, unsigned short* __restrict__ out,
                               int R, int C, int ldin, int ldout, long long sIn, long long sOut)
{
  __shared__ unsigned short t[32][33];
  in  += (long long)blockIdx.z * sIn;
  out += (long long)blockIdx.z * sOut;
  const int c0 = blockIdx.x * 32, r0 = blockIdx.y * 32;
  for (int i = threadIdx.y; i < 32; i += 8) {
    const int r = r0 + i, c = c0 + threadIdx.x;
    if (r < R && c < C) t[i][threadIdx.x] = in[(long long)r * ldin + c];
  }
  __syncthreads();
  for (int i = threadIdx.y; i < 32; i += 8) {
    const int r = c0 + i, c = r0 + threadIdx.x;
    if (r < C && c < R) out[(long long)r * ldout + c] = t[threadIdx.x][i];
  }
}

extern "C" void kernel_launch(void* const* d_in, const int* in_sizes, int n_in,
                              void* d_out, int out_size, void* d_ws, size_t ws_size,
                              hipStream_t stream)
{
  const float* x      = (const float*)d_in[0];
  const float* W_qkv  = (const float*)d_in[1];
  const float* b_qkv  = (const float*)d_in[2];
  const float* W_proj = (const float*)d_in[3];
  const float* b_proj = (const float*)d_in[4];
  const float* W_gp   = (const float*)d_in[5];
  const float* alpha  = (const float*)d_in[6];

  char* p = (char*)d_ws;
  auto alloc = [&](size_t bytes) { char* r = p; p += (bytes + 255) & ~255ULL; return r; };
  unsigned short* qkv    = (unsigned short*)alloc(16384ULL * 2304 * 2);   // q|k|v interleaved rows
  unsigned short* xb     = (unsigned short*)alloc(16384ULL * 768 * 2);
  unsigned short* WqkvT  = (unsigned short*)alloc(2304ULL * 768 * 2);
  unsigned short* WprojT = (unsigned short*)alloc(768ULL * 768 * 2);
  unsigned short* WgpT   = (unsigned short*)alloc(49ULL * 768 * 2);
  unsigned short* gwbuf  = (unsigned short*)alloc(16384ULL * 64 * 2);
  float*          Lbuf   = (float*)alloc(16384ULL * 4);
  unsigned short* wmat   = (unsigned short*)alloc(16ULL * 1024 * 1024 * 2);
  unsigned short* vT     = (unsigned short*)alloc(16ULL * 768 * 1024 * 2);

  const dim3 blk256(256);
  const dim3 tb(32, 8);

  // input conversions / transposes (fp32 -> bf16)
  convert_f2b<<<dim3(12288), blk256, 0, stream>>>(x, xb, 16384LL * 768);
  transpose_f2b<<<dim3(72, 24), tb, 0, stream>>>(W_qkv, WqkvT, 768, 2304, 2304, 768);
  transpose_f2b<<<dim3(24, 24), tb, 0, stream>>>(W_proj, WprojT, 768, 768, 768, 768);
  transpose_f2b<<<dim3(2, 24), tb, 0, stream>>>(W_gp, WgpT, 768, 49, 49, 768);

  // qkv = x @ W_qkv + b_qkv   (M=16384, N=2304, K=768), bf16 out
  gemm_bt<<<dim3(18, 128, 1), blk256, 0, stream>>>(xb, WqkvT, qkv, (float*)0, (const float*)0, b_qkv,
                                                   768, 768, 768, 2304, 0, 0, 0, 0);

  // vT[b][768][1024] = v^T (v = qkv cols 1536..2303)
  transpose_bf16<<<dim3(24, 32, 16), tb, 0, stream>>>(qkv + 1536, vT, 1024, 768, 2304, 1024,
                                                      1024LL * 2304, 768LL * 1024);

  // gw = softmax(q @ W_gp), padded to 64
  gw_kernel<<<dim3(4096), blk256, 0, stream>>>(qkv, WgpT, gwbuf);

  hipMemsetAsync(Lbuf, 0, 16384 * 4, stream);

  // weights (unnormalized) + L
  score_weights<<<dim3(8, 8, 16), blk256, 0, stream>>>(qkv, gwbuf, wmat, Lbuf, alpha);

  // attn_out = (weights @ v) / L  -> written into qkv's dead k-columns (bf16)
  gemm_bt<<<dim3(6, 8, 16), blk256, 0, stream>>>(wmat, vT, qkv + 768, (float*)0, Lbuf, (const float*)0,
                                                 1024, 1024, 1024, 2304,
                                                 1024LL * 1024, 768LL * 1024, 1024LL * 2304, 1024);

  // out = attn_out @ W_proj + b_proj  (fp32 out)
  gemm_bt<<<dim3(6, 128, 1), blk256, 0, stream>>>(qkv + 768, WprojT, (unsigned short*)0, (float*)d_out,
                                                  (const float*)0, b_proj,
                                                  768, 2304, 768, 768, 0, 0, 0, 0);
}